// Round 1
// baseline (1012.907 us; speedup 1.0000x reference)
//
#include <hip/hip_runtime.h>
#include <climits>

// CenterDependentPool2D: out[b,c,oy,ox] = max over k(oy,ox) x k window of
// reflect-padded input at stride 2, where k depends on radius from (112,112):
//   d2 < 60^2  -> k=2
//   d2 < 75^2  -> k=8
//   d2 < 90^2  -> k=14
//   d2 < 105^2 -> k=20
//   else       -> k=26
// pad_lo = (k-1)/2, window x-range = [2*ox - pad_lo, 2*ox - pad_lo + k)

#define IN_SZ 448
#define OUT_SZ 224
#define CENTER 112
#define TILE 32
#define NTX 32
#define NTY 8
#define RPT 4            // output rows per thread (32 / 8)
#define SPAN_MAX 88      // 62 + 26
#define TSTR 89          // padded LDS row stride for tile

__device__ __forceinline__ int reflect448(int g) {
    g = (g < 0) ? -g : g;
    g = (g >= IN_SZ) ? (2 * IN_SZ - 2 - g) : g;
    return g;
}

template <int K>
__device__ __forceinline__ void region_pass(
    const float* __restrict__ T, float* __restrict__ H,
    int plt, int tx, int ty, const int* regk, float* res)
{
    const int pl = (K - 1) >> 1;
    const int off = plt - pl;   // >= 0: shift into the (larger) tile frame
    // ---- horizontal pass: H[ly][tx] = max over K consecutive T elems ----
    for (int ly = off + ty; ly < off + 62 + K; ly += NTY) {
        const float* trow = &T[ly * TSTR + 2 * tx + off];
        float m = trow[0];
#pragma unroll
        for (int q = 1; q < K; ++q) m = fmaxf(m, trow[q]);
        H[ly * NTX + tx] = m;
    }
    __syncthreads();
    // ---- vertical pass: only threads whose pixel belongs to this ring ----
#pragma unroll
    for (int j = 0; j < RPT; ++j) {
        if (regk[j] == K) {
            const int ly0 = 2 * (ty + j * NTY) + off;
            const float* hp = &H[ly0 * NTX + tx];
            float m = hp[0];
#pragma unroll
            for (int r = 1; r < K; ++r) m = fmaxf(m, hp[r * NTX]);
            res[j] = m;
        }
    }
    __syncthreads();   // H reused by next ring pass
}

__global__ __launch_bounds__(256)
void CenterDependentPool2D_kernel(const float* __restrict__ x,
                                  float* __restrict__ out)
{
    __shared__ float T[SPAN_MAX * TSTR];   // 31,328 B
    __shared__ float H[SPAN_MAX * NTX];    // 11,264 B

    const int tx = threadIdx.x;            // 0..31
    const int ty = threadIdx.y;            // 0..7
    const int plane = blockIdx.z;          // b*64 + c, 512 planes
    const int ox0 = blockIdx.x * TILE;
    const int oy0 = blockIdx.y * TILE;

    const float* __restrict__ in = x + (size_t)plane * IN_SZ * IN_SZ;
    float* __restrict__ op = out + (size_t)plane * OUT_SZ * OUT_SZ;

    // ---- radius^2 range over this tile's output rectangle ----
    auto axis_rng = [](int lo) {
        int a = lo - CENTER, b = lo + TILE - 1 - CENTER;
        int mn, mx;
        if (a > 0)      { mn = a;  mx = b; }
        else if (b < 0) { mn = -b; mx = -a; }
        else            { mn = 0;  mx = (-a > b) ? -a : b; }
        return make_int2(mn * mn, mx * mx);
    };
    const int2 xr = axis_rng(ox0), yr = axis_rng(oy0);
    const int d2min = xr.x + yr.x;
    const int d2max = xr.y + yr.y;

    // ring boundaries (squared radii), strict '<' like skimage disk
    const int R2a[5] = {0, 3600, 5625, 8100, 11025};
    const int R2b[5] = {3600, 5625, 8100, 11025, INT_MAX};
    const int KS[5]  = {2, 8, 14, 20, 26};

    bool pres[5];
    int kmax = 2;
#pragma unroll
    for (int i = 0; i < 5; ++i) {
        pres[i] = (d2min < R2b[i]) && (d2max >= R2a[i]);
        if (pres[i]) kmax = KS[i];
    }
    const int plt  = (kmax - 1) >> 1;      // tile-frame pad_lo
    const int span = 62 + kmax;            // input halo span
    const int x_org = 2 * ox0 - plt;
    const int y_org = 2 * oy0 - plt;

    // ---- load halo tile into LDS with reflect mapping ----
    for (int ly = ty; ly < span; ly += NTY) {
        const int gy = reflect448(y_org + ly);
        const float* rowp = in + (size_t)gy * IN_SZ;
        for (int lx = tx; lx < span; lx += NTX) {
            const int gx = reflect448(x_org + lx);
            T[ly * TSTR + lx] = rowp[gx];
        }
    }

    // ---- per-output-pixel ring selection ----
    const int ox = ox0 + tx;
    const int dx2 = (ox - CENTER) * (ox - CENTER);
    int regk[RPT];
    float res[RPT];
#pragma unroll
    for (int j = 0; j < RPT; ++j) {
        const int oy = oy0 + ty + j * NTY;
        const int d2 = (oy - CENTER) * (oy - CENTER) + dx2;
        int k = 26;
        if      (d2 < 3600)  k = 2;
        else if (d2 < 5625)  k = 8;
        else if (d2 < 8100)  k = 14;
        else if (d2 < 11025) k = 20;
        regk[j] = k;
    }

    __syncthreads();

    if (pres[0]) region_pass<2 >(T, H, plt, tx, ty, regk, res);
    if (pres[1]) region_pass<8 >(T, H, plt, tx, ty, regk, res);
    if (pres[2]) region_pass<14>(T, H, plt, tx, ty, regk, res);
    if (pres[3]) region_pass<20>(T, H, plt, tx, ty, regk, res);
    if (pres[4]) region_pass<26>(T, H, plt, tx, ty, regk, res);

    // ---- store ----
#pragma unroll
    for (int j = 0; j < RPT; ++j) {
        const int oy = oy0 + ty + j * NTY;
        op[(size_t)oy * OUT_SZ + ox] = res[j];
    }
}

extern "C" void kernel_launch(void* const* d_in, const int* in_sizes, int n_in,
                              void* d_out, int out_size, void* d_ws, size_t ws_size,
                              hipStream_t stream) {
    const float* x = (const float*)d_in[0];
    float* out = (float*)d_out;
    dim3 grid(OUT_SZ / TILE, OUT_SZ / TILE, 8 * 64);   // (7, 7, 512)
    dim3 block(NTX, NTY, 1);
    hipLaunchKernelGGL(CenterDependentPool2D_kernel, grid, block, 0, stream, x, out);
}

// Round 2
// 981.299 us; speedup vs baseline: 1.0322x; 1.0322x over previous
//
#include <hip/hip_runtime.h>
#include <climits>

// CenterDependentPool2D: out[b,c,oy,ox] = max over k(oy,ox) x k window of
// reflect-padded input at stride 2, k by radius from (112,112):
//   d2 < 60^2 -> 2 | < 75^2 -> 8 | < 90^2 -> 14 | < 105^2 -> 20 | else 26
// pad_lo = (k-1)/2. All k even => window of k at ring-local offset o equals
// exactly k/2 aligned pairs of a base-o pair array (exact, no overestimate).

#define IN_SZ 448
#define OUT_SZ 224
#define CENTER 112
#define TILE_X 32
#define TILE_Y 16
#define NTX 32
#define NTY 8
#define RPT 2              // output rows per thread (16 / 8)
#define TSTR 89            // T row stride (88 max span + 1)
#define PESTR 45
#define HSTR 33
#define MAXROWS 56         // 30 + 26

__device__ __forceinline__ int reflect448(int g) {
    g = (g < 0) ? -g : g;
    g = (g >= IN_SZ) ? (2 * IN_SZ - 2 - g) : g;
    return g;
}

template <int N>
__device__ __forceinline__ float tree_max(float* v) {
#pragma unroll
    for (int s = 1; s < N; s *= 2)
#pragma unroll
        for (int i = 0; i + s < N; i += 2 * s) v[i] = fmaxf(v[i], v[i + s]);
    return v[0];
}

template <int K>
__device__ __forceinline__ void ring_pass(
    const float* __restrict__ T, float* __restrict__ PE, float* __restrict__ H,
    int kmax, int tx, int ty, const int* regk, float* res)
{
    constexpr int KH = K / 2;
    const int o = (kmax - K) >> 1;          // ring-local frame offset (both axes)
    constexpr int NR = 2 * (TILE_Y - 1) + K; // H rows needed = 30 + K
    constexpr int NJ = (TILE_X - 1) + KH;    // PE cols needed = 31 + K/2

    // ---- horizontal pair pre-reduce (stride-1 writes, b64-ish reads) ----
    for (int r = ty; r < NR; r += NTY) {
        const float* trow = &T[(o + r) * TSTR + o];
        float* pe = &PE[r * PESTR];
        for (int j = tx; j < NJ; j += NTX)
            pe[j] = fmaxf(trow[2 * j], trow[2 * j + 1]);
    }
    __syncthreads();

    // ---- horizontal window: K/2 stride-1 conflict-free reads ----
    for (int r = ty; r < NR; r += NTY) {
        const float* pe = &PE[r * PESTR + tx];
        float v[KH];
#pragma unroll
        for (int i = 0; i < KH; ++i) v[i] = pe[i];
        H[r * HSTR + tx] = tree_max<KH>(v);
    }
    __syncthreads();

    // ---- vertical pair pre-reduce (VP aliases PE: PE is dead now) ----
    float* VP = PE;
    constexpr int NV = (TILE_Y - 1) + KH;    // 15 + K/2
    for (int r = ty; r < NV; r += NTY) {
        VP[r * HSTR + tx] =
            fmaxf(H[(2 * r) * HSTR + tx], H[(2 * r + 1) * HSTR + tx]);
    }
    __syncthreads();

    // ---- vertical window: K/2 reads, only owning threads ----
#pragma unroll
    for (int j = 0; j < RPT; ++j) {
        if (regk[j] == K) {
            const float* vp = &VP[(ty + j * NTY) * HSTR + tx];
            float v[KH];
#pragma unroll
            for (int i = 0; i < KH; ++i) v[i] = vp[i * HSTR];
            res[j] = tree_max<KH>(v);
        }
    }
    __syncthreads();   // VP (=PE) reused by next ring
}

__global__ __launch_bounds__(256, 4)
void CenterDependentPool2D_kernel(const float* __restrict__ x,
                                  float* __restrict__ out)
{
    __shared__ float T[MAXROWS * TSTR];    // 19,936 B
    __shared__ float PE[MAXROWS * PESTR];  // 10,080 B (reused as VP)
    __shared__ float H[MAXROWS * HSTR];    //  7,392 B

    const int tx = threadIdx.x;            // 0..31
    const int ty = threadIdx.y;            // 0..7
    const int plane = blockIdx.z;          // b*64 + c
    const int ox0 = blockIdx.x * TILE_X;
    const int oy0 = blockIdx.y * TILE_Y;

    const float* __restrict__ in = x + (size_t)plane * IN_SZ * IN_SZ;
    float* __restrict__ op = out + (size_t)plane * OUT_SZ * OUT_SZ;

    // ---- exact d2 range over tile rectangle ----
    auto axis_rng = [](int lo, int len) {
        int a = lo - CENTER, b = lo + len - 1 - CENTER;
        int mn, mx;
        if (a > 0)      { mn = a;  mx = b; }
        else if (b < 0) { mn = -b; mx = -a; }
        else            { mn = 0;  mx = (-a > b) ? -a : b; }
        return make_int2(mn * mn, mx * mx);
    };
    const int2 xr = axis_rng(ox0, TILE_X), yr = axis_rng(oy0, TILE_Y);
    const int d2min = xr.x + yr.x;
    const int d2max = xr.y + yr.y;

    const int R2a[5] = {0, 3600, 5625, 8100, 11025};
    const int R2b[5] = {3600, 5625, 8100, 11025, INT_MAX};
    const int KS[5]  = {2, 8, 14, 20, 26};

    bool pres[5];
    int kmax = 2;
#pragma unroll
    for (int i = 0; i < 5; ++i) {
        pres[i] = (d2min < R2b[i]) && (d2max >= R2a[i]);
        if (pres[i]) kmax = KS[i];
    }
    const int plt    = (kmax - 1) >> 1;
    const int span_x = 2 * (TILE_X - 1) + kmax;   // <= 88
    const int span_y = 2 * (TILE_Y - 1) + kmax;   // <= 56
    const int x_org  = 2 * ox0 - plt;
    const int y_org  = 2 * oy0 - plt;

    // ---- load halo tile (coalesced rows, reflect at borders) ----
    for (int ly = ty; ly < span_y; ly += NTY) {
        const int gy = reflect448(y_org + ly);
        const float* rowp = in + (size_t)gy * IN_SZ;
        for (int lx = tx; lx < span_x; lx += NTX) {
            const int gx = reflect448(x_org + lx);
            T[ly * TSTR + lx] = rowp[gx];
        }
    }

    // ---- per-pixel ring id ----
    const int ox = ox0 + tx;
    const int dx2 = (ox - CENTER) * (ox - CENTER);
    int regk[RPT];
    float res[RPT];
#pragma unroll
    for (int j = 0; j < RPT; ++j) {
        const int oy = oy0 + ty + j * NTY;
        const int d2 = (oy - CENTER) * (oy - CENTER) + dx2;
        int k = 26;
        if      (d2 < 3600)  k = 2;
        else if (d2 < 5625)  k = 8;
        else if (d2 < 8100)  k = 14;
        else if (d2 < 11025) k = 20;
        regk[j] = k;
    }

    __syncthreads();

    if (pres[0]) ring_pass<2 >(T, PE, H, kmax, tx, ty, regk, res);
    if (pres[1]) ring_pass<8 >(T, PE, H, kmax, tx, ty, regk, res);
    if (pres[2]) ring_pass<14>(T, PE, H, kmax, tx, ty, regk, res);
    if (pres[3]) ring_pass<20>(T, PE, H, kmax, tx, ty, regk, res);
    if (pres[4]) ring_pass<26>(T, PE, H, kmax, tx, ty, regk, res);

    // ---- store (coalesced) ----
#pragma unroll
    for (int j = 0; j < RPT; ++j) {
        const int oy = oy0 + ty + j * NTY;
        op[(size_t)oy * OUT_SZ + ox] = res[j];
    }
}

extern "C" void kernel_launch(void* const* d_in, const int* in_sizes, int n_in,
                              void* d_out, int out_size, void* d_ws, size_t ws_size,
                              hipStream_t stream) {
    const float* x = (const float*)d_in[0];
    float* out = (float*)d_out;
    dim3 grid(OUT_SZ / TILE_X, OUT_SZ / TILE_Y, 8 * 64);   // (7, 14, 512)
    dim3 block(NTX, NTY, 1);
    hipLaunchKernelGGL(CenterDependentPool2D_kernel, grid, block, 0, stream, x, out);
}

// Round 3
// 763.321 us; speedup vs baseline: 1.3270x; 1.2856x over previous
//
#include <hip/hip_runtime.h>
#include <climits>

// CenterDependentPool2D: out[b,c,oy,ox] = max over k x k window (stride 2,
// reflect pad, pad_lo=(k-1)/2) where k by d2 = (oy-112)^2+(ox-112)^2:
//   d2<3600 -> 2 | <5625 -> 8 | <8100 -> 14 | <11025 -> 20 | else 26
// All k even. Tile frame: T row r = input row y_org + r, y_org = 2*oy0 - plt.
// Ring K window start in tile frame = 2*ly + O, O = (kmax-K)/2 (both axes).

#define IN_SZ 448
#define OUT_SZ 224
#define CENTER 112
#define TILE_X 32
#define TILE_Y 16
#define TSTR 92            // multiple of 4 -> f4-aligned T rows
#define NTHREADS 256

__device__ __forceinline__ int reflect448(int g) {
    g = (g < 0) ? -g : g;
    g = (g >= IN_SZ) ? (2 * IN_SZ - 2 - g) : g;
    return g;
}

__device__ __forceinline__ int ring_k(int d2) {
    if (d2 < 3600)  return 2;
    if (d2 < 5625)  return 8;
    if (d2 < 8100)  return 14;
    if (d2 < 11025) return 20;
    return 26;
}

__device__ __forceinline__ int isqrt_floor(int v) {   // exact, v in [0, ~1e6]
    int s = (int)sqrtf((float)v);
    if (s > 0 && s * s > v) --s;
    if ((s + 1) * (s + 1) <= v) ++s;
    return s;
}

__device__ __forceinline__ float4 max4(float4 a, float4 b) {
    return make_float4(fmaxf(a.x, b.x), fmaxf(a.y, b.y),
                       fmaxf(a.z, b.z), fmaxf(a.w, b.w));
}

// One ring: horizontal windows -> H, vertical pairs -> VP, vertical window
// + per-pixel masked store. Row-restricted to output rows [lyA, lyB].
template <int K, int O>
__device__ __forceinline__ void ring_pass(
    const float* __restrict__ T, float* __restrict__ H, float* __restrict__ VP,
    float* __restrict__ op, int tid, int lyA, int lyB, int ox0, int oy0)
{
    constexpr int KH = K / 2;          // pairs per window
    constexpr int S  = O & 3;          // sub-f4 shift of window base
    constexpr int NF = S + K + 6;      // floats needed per 4-output task
    constexpr int R  = (NF + 3) >> 2;  // f4 reads per task
    constexpr int B0 = (O - S) >> 2;   // f4 offset of aligned base

    const int rows  = lyB - lyA + 1;
    const int nh    = 2 * (rows - 1) + K;    // H rows needed
    const int nv    = rows - 1 + KH;         // VP rows needed
    const int tbase = 2 * lyA + O;           // T row of H row 0

    // ---- horizontal windows: 4 outputs per task, aligned f4 reads ----
    for (int t = tid; t < nh * 8; t += NTHREADS) {
        const int hr = t >> 3, g = t & 7;
        const float4* trow = (const float4*)&T[(tbase + hr) * TSTR];
        float f[4 * R];
#pragma unroll
        for (int q = 0; q < R; ++q)
            *(float4*)&f[4 * q] = trow[2 * g + B0 + q];
        float p[KH + 3];                      // register pair pre-reduce
#pragma unroll
        for (int j = 0; j < KH + 3; ++j)
            p[j] = fmaxf(f[S + 2 * j], f[S + 2 * j + 1]);
        float4 W;
        if constexpr (KH == 1) {
            W = make_float4(p[0], p[1], p[2], p[3]);
        } else {                              // KH in {4,7,10,13}
            float core = p[3];
#pragma unroll
            for (int j = 4; j < KH; ++j) core = fmaxf(core, p[j]);
            W.x = fmaxf(fmaxf(p[0], p[1]), fmaxf(p[2], core));
            W.y = fmaxf(fmaxf(p[1], p[2]), fmaxf(core, p[KH]));
            W.z = fmaxf(fmaxf(p[2], core), fmaxf(p[KH], p[KH + 1]));
            W.w = fmaxf(fmaxf(core, p[KH]), fmaxf(p[KH + 1], p[KH + 2]));
        }
        *(float4*)&H[hr * 32 + 4 * g] = W;    // dense, conflict-free
    }
    __syncthreads();

    // ---- vertical pairs of H ----
    for (int t = tid; t < nv * 8; t += NTHREADS) {
        const int v = t >> 3, g = t & 7;
        float4 a = *(const float4*)&H[(2 * v) * 32 + 4 * g];
        float4 b = *(const float4*)&H[(2 * v + 1) * 32 + 4 * g];
        *(float4*)&VP[v * 32 + 4 * g] = max4(a, b);
    }
    __syncthreads();

    // ---- vertical windows + per-pixel masked global store ----
    for (int t = tid; t < rows * 8; t += NTHREADS) {
        const int lr = t >> 3, g = t & 7;
        float4 m = *(const float4*)&VP[lr * 32 + 4 * g];
#pragma unroll
        for (int j = 1; j < KH; ++j)
            m = max4(m, *(const float4*)&VP[(lr + j) * 32 + 4 * g]);
        const int oy  = oy0 + lyA + lr;
        const int dy2 = (oy - CENTER) * (oy - CENTER);
        const int oxb = ox0 + 4 * g;
        float* orow = op + (size_t)oy * OUT_SZ + oxb;
        const float mv[4] = {m.x, m.y, m.z, m.w};
#pragma unroll
        for (int e = 0; e < 4; ++e) {
            const int dx = oxb + e - CENTER;
            if (ring_k(dy2 + dx * dx) == K) orow[e] = mv[e];
        }
    }
    // no trailing sync needed: next ring's H-build writes H (not VP); its
    // post-H barrier orders this V-stage before the next VP overwrite.
}

template <int KMAX>
__device__ __forceinline__ void run_rings(
    const float* T, float* H, float* VP, float* op, int tid,
    const int* lyA, const int* lyB, int ox0, int oy0)
{
    if (lyA[0] <= lyB[0])
        ring_pass<2, (KMAX - 2) / 2>(T, H, VP, op, tid, lyA[0], lyB[0], ox0, oy0);
    if constexpr (KMAX >= 8)
        if (lyA[1] <= lyB[1])
            ring_pass<8, (KMAX - 8) / 2>(T, H, VP, op, tid, lyA[1], lyB[1], ox0, oy0);
    if constexpr (KMAX >= 14)
        if (lyA[2] <= lyB[2])
            ring_pass<14, (KMAX - 14) / 2>(T, H, VP, op, tid, lyA[2], lyB[2], ox0, oy0);
    if constexpr (KMAX >= 20)
        if (lyA[3] <= lyB[3])
            ring_pass<20, (KMAX - 20) / 2>(T, H, VP, op, tid, lyA[3], lyB[3], ox0, oy0);
    if constexpr (KMAX >= 26)
        if (lyA[4] <= lyB[4])
            ring_pass<26, 0>(T, H, VP, op, tid, lyA[4], lyB[4], ox0, oy0);
}

__global__ __launch_bounds__(NTHREADS, 4)
void CenterDependentPool2D_kernel(const float* __restrict__ x,
                                  float* __restrict__ out)
{
    __shared__ float T[56 * TSTR];     // 20,608 B
    __shared__ float H[56 * 32];       //  7,168 B
    __shared__ float VP[28 * 32];      //  3,584 B  -> 31,360 B total

    const int tid = threadIdx.x;
    const int ox0 = blockIdx.x * TILE_X;
    const int oy0 = blockIdx.y * TILE_Y;
    const int plane = blockIdx.z;

    const float* __restrict__ in = x + (size_t)plane * IN_SZ * IN_SZ;
    float* __restrict__ op = out + (size_t)plane * OUT_SZ * OUT_SZ;

    // dx^2 range over this tile's columns
    const int a = ox0 - CENTER, b = ox0 + TILE_X - 1 - CENTER;
    int xmn2, xmx2;
    if (a > 0)      { xmn2 = a * a; xmx2 = b * b; }
    else if (b < 0) { xmn2 = b * b; xmx2 = a * a; }
    else            { xmn2 = 0; const int m = (-a > b) ? -a : b; xmx2 = m * m; }

    const int R2a[5] = {0, 3600, 5625, 8100, 11025};
    const int R2b[5] = {3600, 5625, 8100, 11025, INT_MAX};
    const int KS[5]  = {2, 8, 14, 20, 26};

    // per-ring output-row intervals [lyA, lyB] (conservative-safe; the
    // per-pixel ring_k mask in the V stage guarantees exact coverage)
    int lyA[5], lyB[5];
    int kmax = 2;
    const int d0 = oy0 - CENTER;       // tiles never straddle row 112
#pragma unroll
    for (int i = 0; i < 5; ++i) {
        int A = 1, B = 0;
        int shi;
        bool nonempty;
        if (i == 4) { shi = 1000; nonempty = true; }
        else {
            const int hi2 = R2b[i] - 1 - xmn2;
            nonempty = (hi2 >= 0);
            shi = nonempty ? isqrt_floor(hi2) : 0;
        }
        if (nonempty) {
            const int lo2 = R2a[i] - xmx2;
            const int slo = (lo2 <= 0) ? 0 : isqrt_floor(lo2 - 1) + 1;
            if (d0 >= 0) { A = slo - d0; B = shi - d0; }
            else         { const int dp = -d0; A = dp - shi; B = dp - slo; }
            A = A < 0 ? 0 : A;
            B = B > TILE_Y - 1 ? TILE_Y - 1 : B;
        }
        lyA[i] = A; lyB[i] = B;
        if (A <= B) kmax = KS[i];
    }

    const int plt    = (kmax - 1) >> 1;
    const int span_x = 2 * (TILE_X - 1) + kmax;   // <= 88
    const int span_y = 2 * (TILE_Y - 1) + kmax;   // <= 56
    const int x_org  = 2 * ox0 - plt;
    const int y_org  = 2 * oy0 - plt;
    const int gpr    = (span_x + 3) >> 2;         // f4 groups per row
    const int ntT    = span_y * gpr;

    const bool fast = (x_org >= 0) && ((x_org & 3) == 0) &&
                      (x_org + 4 * gpr <= IN_SZ) &&
                      (y_org >= 0) && (y_org + span_y <= IN_SZ);
    if (fast) {
        for (int t = tid; t < ntT; t += NTHREADS) {
            const int r = t / gpr, c = t - r * gpr;
            const float4 v =
                *(const float4*)(in + (size_t)(y_org + r) * IN_SZ + x_org + 4 * c);
            *(float4*)&T[r * TSTR + 4 * c] = v;
        }
    } else {
        for (int t = tid; t < ntT; t += NTHREADS) {
            const int r = t / gpr, c4 = (t - r * gpr) * 4;
            const float* rowp = in + (size_t)reflect448(y_org + r) * IN_SZ;
            float4 v;
            v.x = rowp[reflect448(x_org + c4 + 0)];
            v.y = rowp[reflect448(x_org + c4 + 1)];
            v.z = rowp[reflect448(x_org + c4 + 2)];
            v.w = rowp[reflect448(x_org + c4 + 3)];
            *(float4*)&T[r * TSTR + c4] = v;
        }
    }
    __syncthreads();

    switch (kmax) {
        case 2:  run_rings<2 >(T, H, VP, op, tid, lyA, lyB, ox0, oy0); break;
        case 8:  run_rings<8 >(T, H, VP, op, tid, lyA, lyB, ox0, oy0); break;
        case 14: run_rings<14>(T, H, VP, op, tid, lyA, lyB, ox0, oy0); break;
        case 20: run_rings<20>(T, H, VP, op, tid, lyA, lyB, ox0, oy0); break;
        default: run_rings<26>(T, H, VP, op, tid, lyA, lyB, ox0, oy0); break;
    }
}

extern "C" void kernel_launch(void* const* d_in, const int* in_sizes, int n_in,
                              void* d_out, int out_size, void* d_ws, size_t ws_size,
                              hipStream_t stream) {
    const float* x = (const float*)d_in[0];
    float* out = (float*)d_out;
    dim3 grid(OUT_SZ / TILE_X, OUT_SZ / TILE_Y, 8 * 64);   // (7, 14, 512)
    dim3 block(NTHREADS, 1, 1);
    hipLaunchKernelGGL(CenterDependentPool2D_kernel, grid, block, 0, stream, x, out);
}